// Round 2
// baseline (324.386 us; speedup 1.0000x reference)
//
#include <hip/hip_runtime.h>

typedef short short8 __attribute__((ext_vector_type(8)));
typedef float floatx4 __attribute__((ext_vector_type(4)));

__device__ __forceinline__ unsigned short f2bf(float f) {
  unsigned u = __float_as_uint(f);
  u += 0x7FFFu + ((u >> 16) & 1u);   // round-to-nearest-even
  return (unsigned short)(u >> 16);
}

// ---------------------------------------------------------------------------
// Kernel 1a: partial projections. part[(which*8+dchunk)*512 + n][c] = sum over
// 256 d of im[n][d]*W[d][c].  grid (8 dchunks, 32 rowtiles(16), 2), 256 thr.
// ---------------------------------------------------------------------------
__global__ __launch_bounds__(256) void proj_partial(
    const float* __restrict__ im_q, const float* __restrict__ im_k,
    const float* __restrict__ Wq, const float* __restrict__ Wk,
    float* __restrict__ part, int* __restrict__ cnt) {
  __shared__ float imS[16 * 260];  // [r][d], stride 260
  const int t = threadIdx.x;
  if (blockIdx.x == 0 && blockIdx.y == 0 && blockIdx.z == 0 && t < 4) cnt[t] = 0;
  const int which = blockIdx.z;
  const float* __restrict__ im = which ? im_k : im_q;
  const float* __restrict__ W  = which ? Wk : Wq;
  const int d0 = blockIdx.x * 256;
  const int row0 = blockIdx.y * 16;
  {
    const int dd0 = (t & 63) * 4;
    const int rb = t >> 6;
#pragma unroll
    for (int p = 0; p < 4; ++p) {
      const int r = p * 4 + rb;
      *(float4*)(imS + r * 260 + dd0) =
          *(const float4*)(im + (size_t)(row0 + r) * 2048 + d0 + dd0);
    }
  }
  __syncthreads();
  const int c4 = (t & 31) * 4;   // 32 col groups * 4 = 128 cols
  const int r2 = (t >> 5) * 2;   // 8 row groups * 2 = 16 rows
  float acc[2][4] = {};
  const float* __restrict__ Wp = W + (size_t)d0 * 128 + c4;
#pragma unroll 8
  for (int d = 0; d < 256; ++d) {
    const float4 w = *(const float4*)(Wp + (size_t)d * 128);
    float a0 = imS[r2 * 260 + d];
    float a1 = imS[(r2 + 1) * 260 + d];
    acc[0][0] += a0 * w.x; acc[0][1] += a0 * w.y;
    acc[0][2] += a0 * w.z; acc[0][3] += a0 * w.w;
    acc[1][0] += a1 * w.x; acc[1][1] += a1 * w.y;
    acc[1][2] += a1 * w.z; acc[1][3] += a1 * w.w;
  }
#pragma unroll
  for (int rr = 0; rr < 2; ++rr) {
    float4 v = make_float4(acc[rr][0], acc[rr][1], acc[rr][2], acc[rr][3]);
    *(float4*)(part + ((size_t)(which * 8 + blockIdx.x) * 512 + row0 + r2 + rr) * 128 + c4) = v;
  }
}

// ---------------------------------------------------------------------------
// Kernel 1b: reduce partials, normalize, l_pos, q->bf16, group lists, labels=0
// ---------------------------------------------------------------------------
__global__ __launch_bounds__(128) void finalize(
    const float* __restrict__ part, const int* __restrict__ label,
    unsigned short* __restrict__ qbf, int* __restrict__ cnt,
    int* __restrict__ rows, float* __restrict__ out) {
  const int n = blockIdx.x, c = threadIdx.x;
  float qraw = 0.f, kraw = 0.f;
#pragma unroll
  for (int ch = 0; ch < 8; ++ch) {
    qraw += part[((size_t)ch * 512 + n) * 128 + c];
    kraw += part[((size_t)(8 + ch) * 512 + n) * 128 + c];
  }
  float sq = qraw * qraw, sk = kraw * kraw, dt = qraw * kraw;
#pragma unroll
  for (int off = 32; off > 0; off >>= 1) {
    sq += __shfl_down(sq, off, 64);
    sk += __shfl_down(sk, off, 64);
    dt += __shfl_down(dt, off, 64);
  }
  __shared__ float sh[3][2];
  const int lane = c & 63, wv = c >> 6;
  if (lane == 0) { sh[0][wv] = sq; sh[1][wv] = sk; sh[2][wv] = dt; }
  __syncthreads();
  const float tsq = sh[0][0] + sh[0][1];
  const float tsk = sh[1][0] + sh[1][1];
  const float tdt = sh[2][0] + sh[2][1];
  const float nq = fmaxf(sqrtf(tsq), 1e-12f);
  const float nk = fmaxf(sqrtf(tsk), 1e-12f);
  qbf[n * 128 + c] = f2bf(qraw / nq);
  if (c == 0) {
    out[(size_t)n * 65537] = tdt / (nq * nk) * (1.0f / 0.07f);   // l_pos / T
    ((int*)out)[(size_t)512 * 65537 + n] = 0;                    // labels
    int g = ((label[n] - 1) % 4 + 4) % 4;
    int pos = atomicAdd(cnt + g, 1);
    rows[g * 512 + pos] = n;
  }
}

// ---------------------------------------------------------------------------
// Kernel 2: grouped GEMM l_neg = Q_g @ queues[g], bf16 MFMA.
// grid (512 col tiles, 4 groups) x 256 thr. A-frags direct from L2 (qbf).
// Bs stride 132: staging b64 writes & frag b64 reads both bank-optimal.
// ---------------------------------------------------------------------------
__global__ __launch_bounds__(256, 3) void moco_lneg(
    const float* __restrict__ queues, const unsigned short* __restrict__ qbf,
    const int* __restrict__ cnt, const int* __restrict__ rows,
    float* __restrict__ out) {
  __shared__ __align__(16) unsigned short Bs[128 * 132];  // [j][c] bf16
  __shared__ int rowsS[512];
  const int g = blockIdx.y;
  const int Mg = cnt[g];
  if (Mg == 0) return;
  const int t = threadIdx.x;
  const int j0 = blockIdx.x * 128;
  rowsS[t] = rows[g * 512 + t];
  rowsS[256 + t] = rows[g * 512 + 256 + t];
  // ---- stage B tile: [c][j] fp32 global -> [j][c] bf16 LDS ----
  {
    const int j = t & 127;
    const int ch = (t >> 7) * 4;   // this thread's c-quad within a pass
    const float* __restrict__ qb = queues + (size_t)g * 128 * 65536 + j0 + j;
#pragma unroll 4
    for (int p = 0; p < 16; ++p) {
      const int c = p * 8 + ch;
      const float f0 = qb[(size_t)c * 65536];
      const float f1 = qb[(size_t)(c + 1) * 65536];
      const float f2 = qb[(size_t)(c + 2) * 65536];
      const float f3 = qb[(size_t)(c + 3) * 65536];
      uint2 u;
      u.x = (unsigned)f2bf(f0) | ((unsigned)f2bf(f1) << 16);
      u.y = (unsigned)f2bf(f2) | ((unsigned)f2bf(f3) << 16);
      *(uint2*)(Bs + j * 132 + c) = u;   // b64, lane bank-stride 2: optimal
    }
  }
  __syncthreads();
  const int lane = t & 63, wave = t >> 6;
  const int qd = lane >> 4, l16 = lane & 15;
  const float invT = 1.0f / 0.07f;
  for (int chunk0 = 0; chunk0 < Mg; chunk0 += 128) {
    const int valid = min(Mg - chunk0, 128);
    floatx4 acc[8][2];
#pragma unroll
    for (int rb = 0; rb < 8; ++rb) {
      floatx4 z = {0.f, 0.f, 0.f, 0.f};
      acc[rb][0] = z; acc[rb][1] = z;
    }
#pragma unroll
    for (int kk = 0; kk < 4; ++kk) {
      const int k0 = kk * 32 + qd * 8;
      short8 bfrag[2];
#pragma unroll
      for (int s = 0; s < 2; ++s) {
        const uint2* p = (const uint2*)(Bs + ((wave * 2 + s) * 16 + l16) * 132 + k0);
        uint2* d = (uint2*)&bfrag[s];
        d[0] = p[0]; d[1] = p[1];
      }
#pragma unroll
      for (int rb = 0; rb < 8; ++rb) {
        const int m = rb * 16 + l16;
        short8 afrag = {};
        if (m < valid) {
          const int rg = rowsS[chunk0 + m];
          *(uint4*)&afrag = *(const uint4*)(qbf + rg * 128 + k0);  // 16B, L2-hit
        }
        acc[rb][0] = __builtin_amdgcn_mfma_f32_16x16x32_bf16(afrag, bfrag[0], acc[rb][0], 0, 0, 0);
        acc[rb][1] = __builtin_amdgcn_mfma_f32_16x16x32_bf16(afrag, bfrag[1], acc[rb][1], 0, 0, 0);
      }
    }
    // ---- epilogue: C/D layout col=lane&15, row=quad*4+reg ----
#pragma unroll
    for (int rb = 0; rb < 8; ++rb) {
#pragma unroll
      for (int r = 0; r < 4; ++r) {
        const int ml = rb * 16 + qd * 4 + r;
        if (ml < valid) {
          const size_t base = (size_t)rowsS[chunk0 + ml] * 65537 + 1 + j0;
#pragma unroll
          for (int s = 0; s < 2; ++s)
            out[base + (wave * 2 + s) * 16 + l16] = acc[rb][s][r] * invT;
        }
      }
    }
  }
}

extern "C" void kernel_launch(void* const* d_in, const int* in_sizes, int n_in,
                              void* d_out, int out_size, void* d_ws, size_t ws_size,
                              hipStream_t stream) {
  const float* im_q   = (const float*)d_in[0];
  const float* im_k   = (const float*)d_in[1];
  const float* Wq     = (const float*)d_in[2];
  const float* Wk     = (const float*)d_in[3];
  const float* queues = (const float*)d_in[4];
  const int*   label  = (const int*)d_in[5];
  float* out = (float*)d_out;

  char* ws = (char*)d_ws;
  float* part = (float*)ws;                                   // 2*8*512*128 f32 = 4 MB
  unsigned short* qbf = (unsigned short*)(ws + (4u << 20));   // 512*128 bf16 = 128 KB
  int* cnt  = (int*)(ws + (4u << 20) + (128u << 10));         // 4 ints
  int* rows = cnt + 4;                                        // 4*512 ints

  proj_partial<<<dim3(8, 32, 2), 256, 0, stream>>>(im_q, im_k, Wq, Wk, part, cnt);
  finalize<<<512, 128, 0, stream>>>(part, label, qbf, cnt, rows, out);
  moco_lneg<<<dim3(512, 4), 256, 0, stream>>>(queues, qbf, cnt, rows, out);
}